// Round 10
// baseline (190.253 us; speedup 1.0000x reference)
//
#include <hip/hip_runtime.h>
#include <hip/hip_bf16.h>
#include <math.h>

#define B_   8
#define N_   4096
#define C_   512
#define H_   8
#define DH_  64
#define TED_ 1280
#define KSEL 409
#define KPAD 448   // 7*64

typedef __attribute__((ext_vector_type(8))) short bf16x8;
typedef __attribute__((ext_vector_type(4))) float f32x4;

// round-to-nearest-even float -> bf16 bits
__device__ __forceinline__ unsigned short f2bf(float f) {
  unsigned u = __float_as_uint(f);
  unsigned r = u + 0x7fffu + ((u >> 16) & 1u);
  return (unsigned short)(r >> 16);
}
__device__ __forceinline__ float bf2f(unsigned short s) {
  return __uint_as_float(((unsigned)s) << 16);
}

__device__ __forceinline__ void gload16(const void* g, void* l) {
  __builtin_amdgcn_global_load_lds(
      (const __attribute__((address_space(1))) void*)g,
      (__attribute__((address_space(3))) void*)l,
      16, 0, 0);
}

// ---------------- gating: scores[b,c] ----------------
__global__ __launch_bounds__(256) void k_gating(const float* __restrict__ temb,
    const float* __restrict__ g_w1, const float* __restrict__ g_b1,
    const float* __restrict__ g_w2, const float* __restrict__ g_b2,
    float* __restrict__ scores)
{
  __shared__ float red[256];
  __shared__ float hid[64];
  int b = blockIdx.x, tid = threadIdx.x;
  int j = tid & 63, part = tid >> 6;
  const float* te = temb + b*TED_;
  float s = 0.f;
  for (int t = part*320; t < part*320 + 320; ++t)
    s += te[t] * g_w1[t*64 + j];
  red[tid] = s;
  __syncthreads();
  if (part == 0) {
    float v = red[j] + red[j+64] + red[j+128] + red[j+192] + g_b1[j];
    hid[j] = v / (1.f + __expf(-v));   // silu
  }
  __syncthreads();
  for (int c = tid; c < C_; c += 256) {
    float s2 = g_b2[c];
    #pragma unroll 8
    for (int h = 0; h < 64; ++h) s2 += hid[h] * g_w2[h*C_ + c];
    scores[b*C_ + c] = s2;
  }
}

// ------- fused: importance dot + LN stats + LN(x)->bf16 (one pass over x) ----
__global__ __launch_bounds__(256) void k_imp_prep(const float* __restrict__ x,
    const float* __restrict__ scores, const float* __restrict__ ln_g,
    const float* __restrict__ ln_b, float* __restrict__ imp,
    unsigned short* __restrict__ xn)
{
  int tid = threadIdx.x, lane = tid & 63, wid = tid >> 6;
  int token = blockIdx.x*4 + wid;
  int b = token >> 12;
  size_t base = (size_t)token*C_ + lane*8;
  float4 v0 = *(const float4*)&x[base];
  float4 v1 = *(const float4*)&x[base + 4];
  const float* sc = scores + b*C_ + lane*8;
  float4 sv0 = *(const float4*)&sc[0];
  float4 sv1 = *(const float4*)&sc[4];
  float si = v0.x*sv0.x + v0.y*sv0.y + v0.z*sv0.z + v0.w*sv0.w
           + v1.x*sv1.x + v1.y*sv1.y + v1.z*sv1.z + v1.w*sv1.w;
  float s1 = v0.x+v0.y+v0.z+v0.w + v1.x+v1.y+v1.z+v1.w;
  float s2 = v0.x*v0.x+v0.y*v0.y+v0.z*v0.z+v0.w*v0.w
           + v1.x*v1.x+v1.y*v1.y+v1.z*v1.z+v1.w*v1.w;
  #pragma unroll
  for (int off = 32; off >= 1; off >>= 1) {
    si += __shfl_xor(si, off, 64);
    s1 += __shfl_xor(s1, off, 64);
    s2 += __shfl_xor(s2, off, 64);
  }
  if (lane == 0) imp[token] = si;
  float m = s1 * (1.f/C_);
  float rs = rsqrtf(s2 * (1.f/C_) - m*m + 1e-5f);
  float4 g0 = *(const float4*)&ln_g[lane*8];
  float4 g1 = *(const float4*)&ln_g[lane*8 + 4];
  float4 b0 = *(const float4*)&ln_b[lane*8];
  float4 b1 = *(const float4*)&ln_b[lane*8 + 4];
  uint4 o;
  o.x = (unsigned)f2bf((v0.x-m)*rs*g0.x + b0.x) | ((unsigned)f2bf((v0.y-m)*rs*g0.y + b0.y) << 16);
  o.y = (unsigned)f2bf((v0.z-m)*rs*g0.z + b0.z) | ((unsigned)f2bf((v0.w-m)*rs*g0.w + b0.w) << 16);
  o.z = (unsigned)f2bf((v1.x-m)*rs*g1.x + b1.x) | ((unsigned)f2bf((v1.y-m)*rs*g1.y + b1.y) << 16);
  o.w = (unsigned)f2bf((v1.z-m)*rs*g1.z + b1.z) | ((unsigned)f2bf((v1.w-m)*rs*g1.w + b1.w) << 16);
  *(uint4*)&xn[base] = o;
}

// ---- deterministic radix-select top-k + inverse map; also zeroes colsum ----
__global__ __launch_bounds__(256) void k_topk(const float* __restrict__ imp,
                                              int* __restrict__ idxout,
                                              int* __restrict__ inv,
                                              float* __restrict__ colsum)
{
  __shared__ unsigned skey[4096];
  __shared__ int hist[256];
  __shared__ unsigned s_prefix;
  __shared__ int s_kneed;
  __shared__ int sc_sel[256], sc_tie[256];
  int b = blockIdx.x, tid = threadIdx.x;
  int lane = tid & 63, wid = tid >> 6;
  colsum[b*C_ + tid] = 0.f;
  colsum[b*C_ + 256 + tid] = 0.f;
  for (int i = tid; i < 4096; i += 256) {
    unsigned u = __float_as_uint(imp[b*N_ + i]);
    skey[i] = (u & 0x80000000u) ? ~u : (u | 0x80000000u);  // monotone key
  }
  if (tid == 0) { s_prefix = 0; s_kneed = KSEL; }
  __syncthreads();
  for (int shift = 24; shift >= 0; shift -= 8) {
    hist[tid] = 0;
    __syncthreads();
    unsigned pref = s_prefix;
    int need0 = s_kneed;
    for (int i = tid; i < 4096; i += 256) {
      unsigned key = skey[i];
      bool match = (shift == 24) || ((key >> (shift + 8)) == pref);
      if (match) atomicAdd(&hist[(key >> shift) & 255], 1);
    }
    __syncthreads();
    if (wid == 0) {   // wave 0: parallel suffix-scan selection
      int h0 = hist[lane*4+0], h1 = hist[lane*4+1];
      int h2 = hist[lane*4+2], h3 = hist[lane*4+3];
      int lt = h0 + h1 + h2 + h3;
      int sfx = lt;
      #pragma unroll
      for (int off = 1; off < 64; off <<= 1) {
        int v = __shfl_down(sfx, off, 64);
        sfx += (lane + off < 64) ? v : 0;
      }
      int e3 = sfx - lt;
      int e2 = e3 + h3;
      int e1 = e2 + h2;
      int e0 = e1 + h1;
      int ej0[4] = {e0, e1, e2, e3};
      int hj0[4] = {h0, h1, h2, h3};
      #pragma unroll
      for (int j = 0; j < 4; ++j) {
        if (ej0[j] < need0 && need0 <= ej0[j] + hj0[j]) {
          s_prefix = (pref << 8) | (unsigned)(lane*4 + j);
          s_kneed = need0 - ej0[j];
        }
      }
    }
    __syncthreads();
  }
  unsigned T = s_prefix;
  int tie_take = s_kneed;
  int lc_sel = 0, lc_tie = 0;
  int i0 = tid * 16;
  for (int e2 = 0; e2 < 16; ++e2) {
    unsigned key = skey[i0 + e2];
    lc_sel += (key > T);
    lc_tie += (key == T);
  }
  sc_sel[tid] = lc_sel; sc_tie[tid] = lc_tie;
  __syncthreads();
  for (int off = 1; off < 256; off <<= 1) {
    int a = 0, c2 = 0;
    if (tid >= off) { a = sc_sel[tid - off]; c2 = sc_tie[tid - off]; }
    __syncthreads();
    sc_sel[tid] += a; sc_tie[tid] += c2;
    __syncthreads();
  }
  int total_gt = sc_sel[255];
  int ps = sc_sel[tid] - lc_sel, pt = sc_tie[tid] - lc_tie;
  for (int e2 = 0; e2 < 16; ++e2) {
    int i = i0 + e2;
    unsigned key = skey[i];
    int v = -1;
    if (key > T) { idxout[b*KSEL + ps] = i; v = ps; ++ps; }
    else if (key == T) {
      if (pt < tie_take) { idxout[b*KSEL + total_gt + pt] = i; v = total_gt + pt; }
      ++pt;
    }
    inv[b*N_ + i] = v;   // aliases imp: own-batch read already done
  }
}

// ------- fp32 -> bf16 convert, 2 row-major arrays (blockIdx.y selects) -----
__global__ __launch_bounds__(256) void k_cvt2(const float* __restrict__ sa,
    const float* __restrict__ sb, unsigned short* __restrict__ da,
    unsigned short* __restrict__ db)
{
  const float* src = blockIdx.y ? sb : sa;
  unsigned short* dst = blockIdx.y ? db : da;
  int i = (blockIdx.x*256 + threadIdx.x)*4;
  float4 v = *(const float4*)&src[i];
  unsigned lo = (unsigned)f2bf(v.x) | ((unsigned)f2bf(v.y) << 16);
  unsigned hi = (unsigned)f2bf(v.z) | ((unsigned)f2bf(v.w) << 16);
  uint2 o; o.x = lo; o.y = hi;
  *(uint2*)&dst[i] = o;
}

// ------- fp32 [512][512] -> bf16 transposed, 4 arrays (blockIdx.y) ---------
__global__ __launch_bounds__(256) void k_cvt_t4(
    const float* __restrict__ w0, const float* __restrict__ w1,
    const float* __restrict__ w2, const float* __restrict__ w3,
    unsigned short* __restrict__ t0, unsigned short* __restrict__ t1,
    unsigned short* __restrict__ t2, unsigned short* __restrict__ t3)
{
  int wsel = blockIdx.y;
  const float* W = (wsel == 0) ? w0 : (wsel == 1) ? w1 : (wsel == 2) ? w2 : w3;
  unsigned short* Wt = (wsel == 0) ? t0 : (wsel == 1) ? t1 : (wsel == 2) ? t2 : t3;
  int idx = blockIdx.x*256 + threadIdx.x;
  int o = idx & 511;
  int ig = (idx >> 9) * 8;
  unsigned short r[8];
  #pragma unroll
  for (int j = 0; j < 8; ++j) r[j] = f2bf(W[(size_t)(ig + j)*512 + o]);
  uint4 v;
  v.x = (unsigned)r[0] | ((unsigned)r[1] << 16);
  v.y = (unsigned)r[2] | ((unsigned)r[3] << 16);
  v.z = (unsigned)r[4] | ((unsigned)r[5] << 16);
  v.w = (unsigned)r[6] | ((unsigned)r[7] << 16);
  *(uint4*)&Wt[(size_t)o*512 + ig] = v;
}

// ---------------- gather routed tokens -> bf16, pad to 448 ----------------
__global__ __launch_bounds__(256) void k_gather(const float* __restrict__ x,
    const int* __restrict__ idx, unsigned short* __restrict__ xg)
{
  int tid = threadIdx.x, lane = tid & 63, wid = tid >> 6;
  int gr = blockIdx.x*4 + wid;
  int b = gr / KPAD, r = gr - b*KPAD;
  uint4 o;
  if (r < KSEL) {
    int tok = idx[b*KSEL + r];
    size_t base = ((size_t)b*N_ + tok)*C_ + lane*8;
    float4 v0 = *(const float4*)&x[base];
    float4 v1 = *(const float4*)&x[base + 4];
    o.x = (unsigned)f2bf(v0.x) | ((unsigned)f2bf(v0.y) << 16);
    o.y = (unsigned)f2bf(v0.z) | ((unsigned)f2bf(v0.w) << 16);
    o.z = (unsigned)f2bf(v1.x) | ((unsigned)f2bf(v1.y) << 16);
    o.w = (unsigned)f2bf(v1.z) | ((unsigned)f2bf(v1.w) << 16);
  } else {
    o.x = o.y = o.z = o.w = 0u;
  }
  *(uint4*)&xg[(size_t)gr*C_ + lane*8] = o;
}

// ------- 256x128 tile single-buffered MFMA body, 512 threads (8 waves) -----
__device__ __forceinline__ void stage256(const unsigned short* __restrict__ Arows,
    const unsigned short* __restrict__ Brows, int k0,
    unsigned short* As, unsigned short* Bs, int srow, int spos)
{
  #pragma unroll
  for (int s = 0; s < 4; ++s) {            // A: 256 rows
    int row = s*64 + srow;
    int chunk = spos ^ (row & 7);
    gload16(&Arows[(size_t)row*C_ + k0 + chunk*8], &As[row*64 + spos*8]);
  }
  #pragma unroll
  for (int s = 0; s < 2; ++s) {            // B: 128 rows
    int row = s*64 + srow;
    int chunk = spos ^ (row & 7);
    gload16(&Brows[(size_t)row*C_ + k0 + chunk*8], &Bs[row*64 + spos*8]);
  }
}

__device__ __forceinline__ void gemm256_body(
    const unsigned short* __restrict__ Arows,
    const unsigned short* __restrict__ Brows,
    unsigned short* As, unsigned short* Bs, f32x4 acc[4][4])
{
  int tid = threadIdx.x;
  int lane = tid & 63, wid = tid >> 6;       // wid 0..7
  int wr = wid >> 1, wc = wid & 1;           // wave tile 64m x 64n of 256x128
  int srow = tid >> 3, spos = tid & 7;       // srow 0..63
  int l15 = lane & 15, lh = lane >> 4;
  for (int k0 = 0; k0 < C_; k0 += 64) {
    stage256(Arows, Brows, k0, As, Bs, srow, spos);
    __syncthreads();
    #pragma unroll
    for (int kk = 0; kk < 2; ++kk) {
      bf16x8 af[4], bfr[4];
      #pragma unroll
      for (int m = 0; m < 4; ++m) {
        int row = wr*64 + m*16 + l15;        // 0..255
        int chunk = (kk*4 + lh) ^ (row & 7);
        af[m] = *(const bf16x8*)&As[row*64 + chunk*8];
      }
      #pragma unroll
      for (int n = 0; n < 4; ++n) {
        int row = wc*64 + n*16 + l15;        // 0..127
        int chunk = (kk*4 + lh) ^ (row & 7);
        bfr[n] = *(const bf16x8*)&Bs[row*64 + chunk*8];
      }
      #pragma unroll
      for (int m = 0; m < 4; ++m)
        #pragma unroll
        for (int n = 0; n < 4; ++n)
          acc[m][n] = __builtin_amdgcn_mfma_f32_16x16x32_bf16(af[m], bfr[n], acc[m][n], 0, 0, 0);
    }
    __syncthreads();
  }
}

// ------- e = xn @ ea_k^T (256-row tile) + fused colsum ---------------------
__global__ __launch_bounds__(512) void k_eak_gemm(
    const unsigned short* __restrict__ A,
    const unsigned short* __restrict__ Bm,
    unsigned short* __restrict__ e, float* __restrict__ colsum)
{
  __shared__ unsigned short As[256*64];
  __shared__ unsigned short Bs[128*64];
  __shared__ float csum[128];
  int tid = threadIdx.x;
  int m0 = blockIdx.x * 256, n0 = blockIdx.y * 128;
  int lane = tid & 63, wid = tid >> 6;
  int wr = wid >> 1, wc = wid & 1;
  int l15 = lane & 15, lh = lane >> 4;
  f32x4 acc[4][4];
  #pragma unroll
  for (int m = 0; m < 4; ++m)
    #pragma unroll
    for (int n = 0; n < 4; ++n) acc[m][n] = (f32x4){0.f,0.f,0.f,0.f};
  gemm256_body(A + (size_t)m0*C_, Bm + (size_t)n0*C_, As, Bs, acc);
  if (tid < 128) csum[tid] = 0.f;
  __syncthreads();
  float pc[4] = {0.f, 0.f, 0.f, 0.f};
  #pragma unroll
  for (int m = 0; m < 4; ++m) {
    int row = m0 + wr*64 + m*16 + lh*4;
    #pragma unroll
    for (int n = 0; n < 4; ++n) {
      int col = n0 + wc*64 + n*16 + l15;
      #pragma unroll
      for (int r = 0; r < 4; ++r) {
        float v = acc[m][n][r] * 0.125f;
        e[(size_t)(row + r)*C_ + col] = f2bf(v);
        pc[n] += __expf(v);
      }
    }
  }
  #pragma unroll
  for (int n = 0; n < 4; ++n)
    atomicAdd(&csum[wc*64 + n*16 + l15], pc[n]);
  __syncthreads();
  int bb = m0 >> 12;   // 4096 rows per batch, 256-row tiles never span batches
  if (tid < 128) atomicAdd(&colsum[bb*C_ + n0 + tid], csum[tid]);
}

// --- ea = a @ ea_v^T with FUSED anorm (softmax value + head-normalize) -----
// A is staged through registers: u = exp(e)/colsum, head-sum over the 64-col
// K-tile (tile == head group exactly), scale, ds_write swizzled.
__global__ __launch_bounds__(512) void k_eav_gemm(
    const unsigned short* __restrict__ e,
    const unsigned short* __restrict__ Bm,
    const float* __restrict__ colsum,
    const int* __restrict__ inv, const float* __restrict__ sad,
    float* __restrict__ Co)
{
  __shared__ unsigned short As[256*64];
  __shared__ unsigned short Bs[128*64];
  int tid = threadIdx.x;
  int m0 = blockIdx.x * 256, n0 = blockIdx.y * 128;
  int lane = tid & 63, wid = tid >> 6;
  int wr = wid >> 1, wc = wid & 1;
  int srow = tid >> 3, spos = tid & 7;
  int l15 = lane & 15, lh = lane >> 4;
  int bb = m0 >> 12;
  const unsigned short* Arows = e + (size_t)m0*C_;
  const unsigned short* Brows = Bm + (size_t)n0*C_;
  f32x4 acc[4][4];
  #pragma unroll
  for (int m = 0; m < 4; ++m)
    #pragma unroll
    for (int n = 0; n < 4; ++n) acc[m][n] = (f32x4){0.f,0.f,0.f,0.f};

  for (int k0 = 0; k0 < C_; k0 += 64) {
    // B tile: direct global->LDS
    #pragma unroll
    for (int s = 0; s < 2; ++s) {
      int row = s*64 + srow;
      int chunk = spos ^ (row & 7);
      gload16(&Brows[(size_t)row*C_ + k0 + chunk*8], &Bs[row*64 + spos*8]);
    }
    // A tile: reg-staged with fused softmax-value + head-normalize.
    // This K-tile covers channels [k0, k0+64) == head k0/64 exactly.
    const float* cs = &colsum[bb*C_ + k0 + spos*8];
    float4 c0 = *(const float4*)&cs[0];
    float4 c1 = *(const float4*)&cs[4];
    #pragma unroll
    for (int s = 0; s < 4; ++s) {
      int row = s*64 + srow;
      uint4 w = *(const uint4*)&Arows[(size_t)row*C_ + k0 + spos*8];
      float u0 = __expf(__uint_as_float(w.x << 16)) / c0.x;
      float u1 = __expf(__uint_as_float(w.x & 0xffff0000u)) / c0.y;
      float u2 = __expf(__uint_as_float(w.y << 16)) / c0.z;
      float u3 = __expf(__uint_as_float(w.y & 0xffff0000u)) / c0.w;
      float u4 = __expf(__uint_as_float(w.z << 16)) / c1.x;
      float u5 = __expf(__uint_as_float(w.z & 0xffff0000u)) / c1.y;
      float u6 = __expf(__uint_as_float(w.w << 16)) / c1.z;
      float u7 = __expf(__uint_as_float(w.w & 0xffff0000u)) / c1.w;
      float hs = u0+u1+u2+u3+u4+u5+u6+u7;
      hs += __shfl_xor(hs, 1, 64);   // row's 8 lanes are contiguous: spos mixes only
      hs += __shfl_xor(hs, 2, 64);
      hs += __shfl_xor(hs, 4, 64);
      float rv = 1.f / (hs + 1e-6f);
      uint4 o;
      o.x = (unsigned)f2bf(u0*rv) | ((unsigned)f2bf(u1*rv) << 16);
      o.y = (unsigned)f2bf(u2*rv) | ((unsigned)f2bf(u3*rv) << 16);
      o.z = (unsigned)f2bf(u4*rv) | ((unsigned)f2bf(u5*rv) << 16);
      o.w = (unsigned)f2bf(u6*rv) | ((unsigned)f2bf(u7*rv) << 16);
      *(uint4*)&As[(size_t)row*64 + (spos ^ (row & 7))*8] = o;
    }
    __syncthreads();
    #pragma unroll
    for (int kk = 0; kk < 2; ++kk) {
      bf16x8 af[4], bfr[4];
      #pragma unroll
      for (int m = 0; m < 4; ++m) {
        int row = wr*64 + m*16 + l15;
        int chunk = (kk*4 + lh) ^ (row & 7);
        af[m] = *(const bf16x8*)&As[row*64 + chunk*8];
      }
      #pragma unroll
      for (int n = 0; n < 4; ++n) {
        int row = wc*64 + n*16 + l15;
        int chunk = (kk*4 + lh) ^ (row & 7);
        bfr[n] = *(const bf16x8*)&Bs[row*64 + chunk*8];
      }
      #pragma unroll
      for (int m = 0; m < 4; ++m)
        #pragma unroll
        for (int n = 0; n < 4; ++n)
          acc[m][n] = __builtin_amdgcn_mfma_f32_16x16x32_bf16(af[m], bfr[n], acc[m][n], 0, 0, 0);
    }
    __syncthreads();
  }

  #pragma unroll
  for (int m = 0; m < 4; ++m) {
    int rowl = wr*64 + m*16 + lh*4;
    #pragma unroll
    for (int r = 0; r < 4; ++r) {
      int row = m0 + rowl + r;            // global token row
      int iv = inv[row];
      int b = row >> 12;
      const float* sap = sad + ((size_t)(b*KPAD) + (iv < 0 ? 0 : iv))*C_;
      #pragma unroll
      for (int n = 0; n < 4; ++n) {
        int col = n0 + wc*64 + n*16 + l15;
        float v = acc[m][n][r];
        if (iv >= 0) v += sap[col];
        Co[(size_t)row*C_ + col] = v;
      }
    }
  }
}

// ------- 2-phase pipelined 128x128 body (64 KB LDS) for small grids --------
__device__ __forceinline__ void stage128(const unsigned short* __restrict__ Arows,
    const unsigned short* __restrict__ Brows, int k0,
    unsigned short* As, unsigned short* Bs, int srow, int spos)
{
  #pragma unroll
  for (int s = 0; s < 4; ++s) {
    int row = s*32 + srow;
    int chunk = spos ^ (row & 7);
    gload16(&Arows[(size_t)row*C_ + k0 + chunk*8], &As[row*64 + spos*8]);
    gload16(&Brows[(size_t)row*C_ + k0 + chunk*8], &Bs[row*64 + spos*8]);
  }
}

__device__ __forceinline__ void gemm128_pipe(
    const unsigned short* __restrict__ Arows,
    const unsigned short* __restrict__ Brows,
    unsigned short* As, unsigned short* Bs,   // each 2*8192 ushorts
    f32x4 acc[4][4])
{
  int tid = threadIdx.x;
  int lane = tid & 63, wid = tid >> 6;
  int wr = wid >> 1, wc = wid & 1;
  int srow = tid >> 3, spos = tid & 7;
  int l15 = lane & 15, lh = lane >> 4;
  stage128(Arows, Brows, 0, As, Bs, srow, spos);
  __syncthreads();
  for (int t = 0; t < 8; ++t) {
    int cur = (t & 1) ? 8192 : 0;
    int nxt = 8192 - cur;
    if (t < 7)
      stage128(Arows, Brows, (t+1)*64, As + nxt, Bs + nxt, srow, spos);
    #pragma unroll
    for (int kk = 0; kk < 2; ++kk) {
      bf16x8 af[4], bfr[4];
      #pragma unroll
      for (int m = 0; m < 4; ++m) {
        int row = wr*64 + m*16 + l15;
        int chunk = (kk*4 + lh) ^ (row & 7);
        af[m] = *(const bf16x8*)&As[cur + row*64 + chunk*8];
      }
      #pragma unroll
      for (int n = 0; n < 4; ++n) {
        int row = wc*64 + n*16 + l15;
        int chunk = (kk*4 + lh) ^ (row & 7);
        bfr[n] = *(const bf16x8*)&Bs[cur + row*64 + chunk*8];
      }
      #pragma unroll
      for (int m = 0; m < 4; ++m)
        #pragma unroll
        for (int n = 0; n < 4; ++n)
          acc[m][n] = __builtin_amdgcn_mfma_f32_16x16x32_bf16(af[m], bfr[n], acc[m][n], 0, 0, 0);
    }
    __syncthreads();
  }
}

// ---- QKV MFMA GEMM: z selects weight; coalesced LDS-repack epilogue ------
__global__ __launch_bounds__(256) void k_qkv_gemm(
    const unsigned short* __restrict__ xg,
    const unsigned short* __restrict__ wqt,
    const unsigned short* __restrict__ wkt,
    const unsigned short* __restrict__ wvt,
    unsigned short* __restrict__ qg, unsigned short* __restrict__ kg,
    unsigned short* __restrict__ vt)
{
  __shared__ unsigned short smem[32768];   // pipe: As|Bs; epilogue: 128x130 tile
  int tid = threadIdx.x;
  int m0 = blockIdx.x * 128, n0 = blockIdx.y * 128, w = blockIdx.z;
  const unsigned short* Wt = (w == 0) ? wqt : (w == 1) ? wkt : wvt;
  int lane = tid & 63, wid = tid >> 6;
  int wr = wid >> 1, wc = wid & 1;
  int l15 = lane & 15, lh = lane >> 4;
  f32x4 acc[4][4];
  #pragma unroll
  for (int m = 0; m < 4; ++m)
    #pragma unroll
    for (int n = 0; n < 4; ++n) acc[m][n] = (f32x4){0.f,0.f,0.f,0.f};
  gemm128_pipe(xg + (size_t)m0*C_, Wt + (size_t)n0*C_, smem, smem + 16384, acc);
  // pipe ends with __syncthreads(): smem free for repack
  float scale = (w == 0) ? 0.125f : 1.f;   // fold DH^-0.5 into Q
  const int TS = 130;                      // padded stride (odd dwords)
  #pragma unroll
  for (int m = 0; m < 4; ++m) {
    int rowl = wr*64 + m*16 + lh*4;
    #pragma unroll
    for (int n = 0; n < 4; ++n) {
      int col = wc*64 + n*16 + l15;
      #pragma unroll
      for (int r = 0; r < 4; ++r)
        smem[(rowl + r)*TS + col] = f2bf(acc[m][n][r] * scale);
    }
  }
  __syncthreads();
  int hbase = n0 >> 6;                     // 2 heads per 128-col tile
  if (w < 2) {
    unsigned short* dst = (w == 0) ? qg : kg;
    #pragma unroll
    for (int it = 0; it < 8; ++it) {
      int u = it*256 + tid;                // 0..2047
      int row = u >> 4, seg = u & 15;
      int mr = m0 + row;
      int b = mr / KPAD, rr = mr - b*KPAD;
      int h = hbase + (seg >> 3);
      int d0 = (seg & 7) * 8;
      const unsigned* sp = (const unsigned*)&smem[row*TS + seg*8];
      uint4 v; v.x = sp[0]; v.y = sp[1]; v.z = sp[2]; v.w = sp[3];
      *(uint4*)&dst[(((size_t)(b*H_ + h))*KPAD + rr)*DH_ + d0] = v;
    }
  } else {
    #pragma unroll
    for (int it = 0; it < 8; ++it) {
      int u = it*256 + tid;
      int d = u >> 4;                      // tile col 0..127
      int tg = u & 15;                     // token group (8 tokens)
      int mr = m0 + tg*8;
      int b = mr / KPAD, rr = mr - b*KPAD; // 8-aligned, never straddles batch
      int h = hbase + (d >> 6);
      int dd = d & 63;
      unsigned short tmp[8];
      #pragma unroll
      for (int k = 0; k < 8; ++k) tmp[k] = smem[(tg*8 + k)*TS + d];
      uint4 v;
      v.x = (unsigned)tmp[0] | ((unsigned)tmp[1] << 16);
      v.y = (unsigned)tmp[2] | ((unsigned)tmp[3] << 16);
      v.z = (unsigned)tmp[4] | ((unsigned)tmp[5] << 16);
      v.w = (unsigned)tmp[6] | ((unsigned)tmp[7] << 16);
      *(uint4*)&vt[(((size_t)(b*H_ + h))*DH_ + dd)*KPAD + rr] = v;
    }
  }
}

// ---------- MFMA flash attention (double-buffered K/V, 1 barrier/tile) -----
__global__ __launch_bounds__(256) void k_attn_mfma(
    const unsigned short* __restrict__ qg, const unsigned short* __restrict__ kg,
    const unsigned short* __restrict__ vt, unsigned short* __restrict__ sab)
{
  __shared__ unsigned short Qs[4096], Ps[4096];
  __shared__ unsigned short Ks[2][4096], Vs[2][4096];
  int tid = threadIdx.x, lane = tid & 63, wid = tid >> 6;
  int qt = blockIdx.x, h = blockIdx.y, b = blockIdx.z;
  int l15 = lane & 15, lh = lane >> 4;
  const unsigned short* qbase = qg + (((size_t)(b*H_ + h))*KPAD + qt*64)*DH_;
  const unsigned short* kbase = kg + ((size_t)(b*H_ + h))*KPAD*DH_;
  const unsigned short* vbase = vt + ((size_t)(b*H_ + h))*DH_*KPAD;
  int c0 = tid, c1 = tid + 256;
  int r0 = c0 >> 3, p0 = c0 & 7;
  int r1 = c1 >> 3, p1 = c1 & 7;
  gload16(&qbase[(size_t)r0*64 + (p0 ^ (r0 & 7))*8], &Qs[c0*8]);
  gload16(&qbase[(size_t)r1*64 + (p1 ^ (r1 & 7))*8], &Qs[c1*8]);
  gload16(&kbase[(size_t)r0*64 + (p0 ^ (r0 & 7))*8], &Ks[0][c0*8]);
  gload16(&kbase[(size_t)r1*64 + (p1 ^ (r1 & 7))*8], &Ks[0][c1*8]);
  gload16(&vbase[(size_t)r0*KPAD + (p0 ^ (r0 & 7))*8], &Vs[0][c0*8]);
  gload16(&vbase[(size_t)r1*KPAD + (p1 ^ (r1 & 7))*8], &Vs[0][c1*8]);
  __syncthreads();

  f32x4 acc_o[4];
  #pragma unroll
  for (int ct = 0; ct < 4; ++ct) acc_o[ct] = (f32x4){0.f,0.f,0.f,0.f};
  float m_run[4], l_run[4];
  #pragma unroll
  for (int r = 0; r < 4; ++r) { m_run[r] = -1e30f; l_run[r] = 0.f; }

  for (int t = 0; t < 7; ++t) {
    int cur = t & 1;
    if (t < 6) {
      int kt1 = (t+1)*64;
      int nb = cur ^ 1;
      gload16(&kbase[((size_t)(kt1 + r0))*64 + (p0 ^ (r0 & 7))*8], &Ks[nb][c0*8]);
      gload16(&kbase[((size_t)(kt1 + r1))*64 + (p1 ^ (r1 & 7))*8], &Ks[nb][c1*8]);
      gload16(&vbase[(size_t)r0*KPAD + kt1 + (p0 ^ (r0 & 7))*8], &Vs[nb][c0*8]);
      gload16(&vbase[(size_t)r1*KPAD + kt1 + (p1 ^ (r1 & 7))*8], &Vs[nb][c1*8]);
    }
    int kt0 = t*64;

    f32x4 s4[4];
    #pragma unroll
    for (int ct = 0; ct < 4; ++ct) s4[ct] = (f32x4){0.f,0.f,0.f,0.f};
    #pragma unroll
    for (int ks = 0; ks < 2; ++ks) {
      int qrow = wid*16 + l15;
      int qch = (ks*4 + lh) ^ (qrow & 7);
      bf16x8 qa = *(const bf16x8*)&Qs[qrow*64 + qch*8];
      #pragma unroll
      for (int ct = 0; ct < 4; ++ct) {
        int krow = ct*16 + l15;
        int kch = (ks*4 + lh) ^ (krow & 7);
        bf16x8 kb8 = *(const bf16x8*)&Ks[cur][krow*64 + kch*8];
        s4[ct] = __builtin_amdgcn_mfma_f32_16x16x32_bf16(qa, kb8, s4[ct], 0, 0, 0);
      }
    }

    bool valid[4];
    #pragma unroll
    for (int ct = 0; ct < 4; ++ct) valid[ct] = (kt0 + ct*16 + l15) < KSEL;
    #pragma unroll
    for (int r = 0; r < 4; ++r) {
      float sv[4];
      #pragma unroll
      for (int ct = 0; ct < 4; ++ct) sv[ct] = valid[ct] ? s4[ct][r] : -1e30f;
      float tm = fmaxf(fmaxf(sv[0], sv[1]), fmaxf(sv[2], sv[3]));
      #pragma unroll
      for (int off = 1; off < 16; off <<= 1) tm = fmaxf(tm, __shfl_xor(tm, off, 64));
      float mnew = fmaxf(m_run[r], tm);
      float corr = __expf(m_run[r] - mnew);
      float rs = 0.f;
      float p[4];
      #pragma unroll
      for (int ct = 0; ct < 4; ++ct) { p[ct] = __expf(sv[ct] - mnew); rs += p[ct]; }
      #pragma unroll
      for (int off = 1; off < 16; off <<= 1) rs += __shfl_xor(rs, off, 64);
      l_run[r] = l_run[r]*corr + rs;
      m_run[r] = mnew;
      #pragma unroll
      for (int ct = 0; ct < 4; ++ct) acc_o[ct][r] *= corr;
      int rowL = wid*16 + lh*4 + r;
      #pragma unroll
      for (int ct = 0; ct < 4; ++ct) {
        int col = ct*16 + l15;
        Ps[rowL*64 + ((col >> 3) ^ (rowL & 7))*8 + (col & 7)] = f2bf(p[ct]);
      }
    }

    #pragma unroll
    for (int ks = 0; ks < 2; ++ks) {
      int prow = wid*16 + l15;
      int pch = (ks*4 + lh) ^ (prow & 7);
      bf16x8 pa = *(const bf16x8*)&Ps[prow*64 + pch*8];
      #pragma unroll
      for (int ct = 0; ct < 4; ++ct) {
        int vrow = ct*16 + l15;
        int vch = (ks*4 + lh) ^ (vrow & 7);
        bf16x8 vb8 = *(const bf16x8*)&Vs[cur][vrow*64 + vch*8];
        acc_o[ct] = __builtin_amdgcn_mfma_f32_16x16x32_bf16(pa, vb8, acc_o[ct], 0, 0, 0);
      }
    }
    __syncthreads();
  }

  #pragma unroll
  for (int r = 0; r < 4; ++r) {
    int rg = qt*64 + wid*16 + lh*4 + r;
    float inv = 1.f / l_run[r];
    #pragma unroll
    for (int ct = 0; ct < 4; ++ct) {
      int col = h*64 + ct*16 + l15;
      unsigned short v = (rg < KSEL) ? f2bf(acc_o[ct][r] * inv) : (unsigned short)0;
      sab[((size_t)b*KPAD + rg)*C_ + col] = v;
    }
  }
}

// -------- out-proj MFMA GEMM -> DENSE sa_out = alpha*(sa@wo + bo) ----------
__global__ __launch_bounds__(256) void k_saout_gemm(
    const unsigned short* __restrict__ sab,
    const unsigned short* __restrict__ wot,
    const float* __restrict__ bo,
    const float* __restrict__ alphap, float* __restrict__ sad)
{
  __shared__ unsigned short As[2*8192];
  __shared__ unsigned short Bs[2*8192];
  int tid = threadIdx.x;
  int m0 = blockIdx.x * 128, n0 = blockIdx.y * 128;
  int lane = tid & 63, wid = tid >> 6;
  int wr = wid >> 1, wc = wid & 1;
  int l15 = lane & 15, lh = lane >> 4;
  f32x4 acc[4][4];
  #pragma unroll
  for (int m = 0; m < 4; ++m)
    #pragma unroll
    for (int n = 0; n < 4; ++n) acc[m][n] = (f32x4){0.f,0.f,0.f,0.f};
  gemm128_pipe(sab + (size_t)m0*C_, wot + (size_t)n0*C_, As, Bs, acc);
  float alpha = alphap[0];
  #pragma unroll
  for (int m = 0; m < 4; ++m) {
    int rowl = wr*64 + m*16 + lh*4;
    #pragma unroll
    for (int r = 0; r < 4; ++r) {
      int mr = m0 + rowl + r;            // = b*KPAD + rr
      #pragma unroll
      for (int n = 0; n < 4; ++n) {
        int col = n0 + wc*64 + n*16 + l15;
        sad[(size_t)mr*C_ + col] = alpha*(acc[m][n][r] + bo[col]);
      }
    }
  }
}

extern "C" void kernel_launch(void* const* d_in, const int* in_sizes, int n_in,
                              void* d_out, int out_size, void* d_ws, size_t ws_size,
                              hipStream_t stream)
{
  const float* x     = (const float*)d_in[0];
  const float* temb  = (const float*)d_in[1];
  const float* g_w1  = (const float*)d_in[2];
  const float* g_b1  = (const float*)d_in[3];
  const float* g_w2  = (const float*)d_in[4];
  const float* g_b2  = (const float*)d_in[5];
  const float* wq    = (const float*)d_in[6];
  const float* wk    = (const float*)d_in[7];
  const float* wv    = (const float*)d_in[8];
  const float* wo    = (const float*)d_in[9];
  const float* bo    = (const float*)d_in[10];
  const float* ln_g  = (const float*)d_in[11];
  const float* ln_b  = (const float*)d_in[12];
  const float* ea_k  = (const float*)d_in[13];
  const float* ea_v  = (const float*)d_in[14];
  const float* alpha = (const float*)d_in[15];
  float* out = (float*)d_out;
  float* ws = (float*)d_ws;

  // workspace layout (float offsets)
  float* scores  = ws;                          // 4096 (dead after imp_prep)
  float* colsum  = ws;                          // alias (zeroed in topk)
  float* imp     = ws + 4096;                   // 32768 (dead after topk)
  int*   invm    = (int*)(ws + 4096);           // alias imp: inverse token map
  int*   idx     = (int*)(ws + 102400);         // 4096
  unsigned short* ebuf = (unsigned short*)(ws + 106496);    // 16777216 bf16
  unsigned short* xnb  = (unsigned short*)(ws + 8495104);   // 16777216 bf16 (xn)
  unsigned short* eakb = (unsigned short*)(ws + 16883712);  // 262144 bf16
  unsigned short* eavb = (unsigned short*)(ws + 17014784);
  unsigned short* wqt  = (unsigned short*)(ws + 17145856);
  unsigned short* wkt  = (unsigned short*)(ws + 17276928);
  unsigned short* wvt  = (unsigned short*)(ws + 17408000);
  unsigned short* wot  = (unsigned short*)(ws + 17539072);
  unsigned short* xg   = (unsigned short*)(ws + 17670144);  // [8*448][512] bf16
  unsigned short* qg   = (unsigned short*)(ws + 18587648);  // [8][8][448][64] (dead after attn)
  unsigned short* kg   = (unsigned short*)(ws + 19505152);  //                 (dead after attn)
  unsigned short* vtb  = (unsigned short*)(ws + 20422656);  // [8][8][64][448] (dead after attn)
  unsigned short* sab  = (unsigned short*)(ws + 21340160);  // [8*448][512]
  float* sad = ws + 18587648;                   // dense SA out [8*448][512] f32, over qg/kg

  k_gating     <<<dim3(B_),          dim3(256), 0, stream>>>(temb, g_w1, g_b1, g_w2, g_b2, scores);
  k_imp_prep   <<<dim3(B_*N_/4),     dim3(256), 0, stream>>>(x, scores, ln_g, ln_b, imp, xnb);
  k_topk       <<<dim3(B_),          dim3(256), 0, stream>>>(imp, idx, invm, colsum);
  k_cvt2       <<<dim3(256, 2),      dim3(256), 0, stream>>>(ea_k, ea_v, eakb, eavb);
  k_cvt_t4     <<<dim3(128, 4),      dim3(256), 0, stream>>>(wq, wk, wv, wo, wqt, wkt, wvt, wot);
  k_gather     <<<dim3(B_*KPAD/4),   dim3(256), 0, stream>>>(x, idx, xg);
  k_qkv_gemm   <<<dim3(28, 4, 3),    dim3(256), 0, stream>>>(xg, wqt, wkt, wvt, qg, kg, vtb);
  k_attn_mfma  <<<dim3(7, H_, B_),   dim3(256), 0, stream>>>(qg, kg, vtb, sab);
  k_eak_gemm   <<<dim3(128, 4),      dim3(512), 0, stream>>>(xnb, eakb, ebuf, colsum);
  k_saout_gemm <<<dim3(28, 4),       dim3(256), 0, stream>>>(sab, wot, bo, alpha, sad);
  k_eav_gemm   <<<dim3(128, 4),      dim3(512), 0, stream>>>(ebuf, eavb, colsum, invm, sad, out);
}

// Round 11
// 166.578 us; speedup vs baseline: 1.1421x; 1.1421x over previous
//
#include <hip/hip_runtime.h>
#include <hip/hip_bf16.h>
#include <math.h>

#define B_   8
#define N_   4096
#define C_   512
#define H_   8
#define DH_  64
#define TED_ 1280
#define KSEL 409
#define KPAD 448   // 7*64

typedef __attribute__((ext_vector_type(8))) short bf16x8;
typedef __attribute__((ext_vector_type(4))) float f32x4;

// round-to-nearest-even float -> bf16 bits
__device__ __forceinline__ unsigned short f2bf(float f) {
  unsigned u = __float_as_uint(f);
  unsigned r = u + 0x7fffu + ((u >> 16) & 1u);
  return (unsigned short)(r >> 16);
}
__device__ __forceinline__ float bf2f(unsigned short s) {
  return __uint_as_float(((unsigned)s) << 16);
}

__device__ __forceinline__ void gload16(const void* g, void* l) {
  __builtin_amdgcn_global_load_lds(
      (const __attribute__((address_space(1))) void*)g,
      (__attribute__((address_space(3))) void*)l,
      16, 0, 0);
}

// ---------------- gating: scores[b,c] ----------------
__global__ __launch_bounds__(256) void k_gating(const float* __restrict__ temb,
    const float* __restrict__ g_w1, const float* __restrict__ g_b1,
    const float* __restrict__ g_w2, const float* __restrict__ g_b2,
    float* __restrict__ scores)
{
  __shared__ float red[256];
  __shared__ float hid[64];
  int b = blockIdx.x, tid = threadIdx.x;
  int j = tid & 63, part = tid >> 6;
  const float* te = temb + b*TED_;
  float s = 0.f;
  for (int t = part*320; t < part*320 + 320; ++t)
    s += te[t] * g_w1[t*64 + j];
  red[tid] = s;
  __syncthreads();
  if (part == 0) {
    float v = red[j] + red[j+64] + red[j+128] + red[j+192] + g_b1[j];
    hid[j] = v / (1.f + __expf(-v));   // silu
  }
  __syncthreads();
  for (int c = tid; c < C_; c += 256) {
    float s2 = g_b2[c];
    #pragma unroll 8
    for (int h = 0; h < 64; ++h) s2 += hid[h] * g_w2[h*C_ + c];
    scores[b*C_ + c] = s2;
  }
}

// ------- fused: importance dot + LN stats + LN(x)->bf16 (one pass over x) ----
__global__ __launch_bounds__(256) void k_imp_prep(const float* __restrict__ x,
    const float* __restrict__ scores, const float* __restrict__ ln_g,
    const float* __restrict__ ln_b, float* __restrict__ imp,
    unsigned short* __restrict__ xn)
{
  int tid = threadIdx.x, lane = tid & 63, wid = tid >> 6;
  int token = blockIdx.x*4 + wid;
  int b = token >> 12;
  size_t base = (size_t)token*C_ + lane*8;
  float4 v0 = *(const float4*)&x[base];
  float4 v1 = *(const float4*)&x[base + 4];
  const float* sc = scores + b*C_ + lane*8;
  float4 sv0 = *(const float4*)&sc[0];
  float4 sv1 = *(const float4*)&sc[4];
  float si = v0.x*sv0.x + v0.y*sv0.y + v0.z*sv0.z + v0.w*sv0.w
           + v1.x*sv1.x + v1.y*sv1.y + v1.z*sv1.z + v1.w*sv1.w;
  float s1 = v0.x+v0.y+v0.z+v0.w + v1.x+v1.y+v1.z+v1.w;
  float s2 = v0.x*v0.x+v0.y*v0.y+v0.z*v0.z+v0.w*v0.w
           + v1.x*v1.x+v1.y*v1.y+v1.z*v1.z+v1.w*v1.w;
  #pragma unroll
  for (int off = 32; off >= 1; off >>= 1) {
    si += __shfl_xor(si, off, 64);
    s1 += __shfl_xor(s1, off, 64);
    s2 += __shfl_xor(s2, off, 64);
  }
  if (lane == 0) imp[token] = si;
  float m = s1 * (1.f/C_);
  float rs = rsqrtf(s2 * (1.f/C_) - m*m + 1e-5f);
  float4 g0 = *(const float4*)&ln_g[lane*8];
  float4 g1 = *(const float4*)&ln_g[lane*8 + 4];
  float4 b0 = *(const float4*)&ln_b[lane*8];
  float4 b1 = *(const float4*)&ln_b[lane*8 + 4];
  uint4 o;
  o.x = (unsigned)f2bf((v0.x-m)*rs*g0.x + b0.x) | ((unsigned)f2bf((v0.y-m)*rs*g0.y + b0.y) << 16);
  o.y = (unsigned)f2bf((v0.z-m)*rs*g0.z + b0.z) | ((unsigned)f2bf((v0.w-m)*rs*g0.w + b0.w) << 16);
  o.z = (unsigned)f2bf((v1.x-m)*rs*g1.x + b1.x) | ((unsigned)f2bf((v1.y-m)*rs*g1.y + b1.y) << 16);
  o.w = (unsigned)f2bf((v1.z-m)*rs*g1.z + b1.z) | ((unsigned)f2bf((v1.w-m)*rs*g1.w + b1.w) << 16);
  *(uint4*)&xn[base] = o;
}

// ---- deterministic radix-select top-k + inverse map; also zeroes colsum ----
__global__ __launch_bounds__(256) void k_topk(const float* __restrict__ imp,
                                              int* __restrict__ idxout,
                                              int* __restrict__ inv,
                                              float* __restrict__ colsum)
{
  __shared__ unsigned skey[4096];
  __shared__ int hist[256];
  __shared__ unsigned s_prefix;
  __shared__ int s_kneed;
  __shared__ int sc_sel[256], sc_tie[256];
  int b = blockIdx.x, tid = threadIdx.x;
  int lane = tid & 63, wid = tid >> 6;
  colsum[b*C_ + tid] = 0.f;
  colsum[b*C_ + 256 + tid] = 0.f;
  for (int i = tid; i < 4096; i += 256) {
    unsigned u = __float_as_uint(imp[b*N_ + i]);
    skey[i] = (u & 0x80000000u) ? ~u : (u | 0x80000000u);  // monotone key
  }
  if (tid == 0) { s_prefix = 0; s_kneed = KSEL; }
  __syncthreads();
  for (int shift = 24; shift >= 0; shift -= 8) {
    hist[tid] = 0;
    __syncthreads();
    unsigned pref = s_prefix;
    int need0 = s_kneed;
    for (int i = tid; i < 4096; i += 256) {
      unsigned key = skey[i];
      bool match = (shift == 24) || ((key >> (shift + 8)) == pref);
      if (match) atomicAdd(&hist[(key >> shift) & 255], 1);
    }
    __syncthreads();
    if (wid == 0) {   // wave 0: parallel suffix-scan selection
      int h0 = hist[lane*4+0], h1 = hist[lane*4+1];
      int h2 = hist[lane*4+2], h3 = hist[lane*4+3];
      int lt = h0 + h1 + h2 + h3;
      int sfx = lt;
      #pragma unroll
      for (int off = 1; off < 64; off <<= 1) {
        int v = __shfl_down(sfx, off, 64);
        sfx += (lane + off < 64) ? v : 0;
      }
      int e3 = sfx - lt;
      int e2 = e3 + h3;
      int e1 = e2 + h2;
      int e0 = e1 + h1;
      int ej0[4] = {e0, e1, e2, e3};
      int hj0[4] = {h0, h1, h2, h3};
      #pragma unroll
      for (int j = 0; j < 4; ++j) {
        if (ej0[j] < need0 && need0 <= ej0[j] + hj0[j]) {
          s_prefix = (pref << 8) | (unsigned)(lane*4 + j);
          s_kneed = need0 - ej0[j];
        }
      }
    }
    __syncthreads();
  }
  unsigned T = s_prefix;
  int tie_take = s_kneed;
  int lc_sel = 0, lc_tie = 0;
  int i0 = tid * 16;
  for (int e2 = 0; e2 < 16; ++e2) {
    unsigned key = skey[i0 + e2];
    lc_sel += (key > T);
    lc_tie += (key == T);
  }
  sc_sel[tid] = lc_sel; sc_tie[tid] = lc_tie;
  __syncthreads();
  for (int off = 1; off < 256; off <<= 1) {
    int a = 0, c2 = 0;
    if (tid >= off) { a = sc_sel[tid - off]; c2 = sc_tie[tid - off]; }
    __syncthreads();
    sc_sel[tid] += a; sc_tie[tid] += c2;
    __syncthreads();
  }
  int total_gt = sc_sel[255];
  int ps = sc_sel[tid] - lc_sel, pt = sc_tie[tid] - lc_tie;
  for (int e2 = 0; e2 < 16; ++e2) {
    int i = i0 + e2;
    unsigned key = skey[i];
    int v = -1;
    if (key > T) { idxout[b*KSEL + ps] = i; v = ps; ++ps; }
    else if (key == T) {
      if (pt < tie_take) { idxout[b*KSEL + total_gt + pt] = i; v = total_gt + pt; }
      ++pt;
    }
    inv[b*N_ + i] = v;   // aliases imp: own-batch read already done
  }
}

// ------- fp32 -> bf16 convert, 2 row-major arrays (blockIdx.y selects) -----
__global__ __launch_bounds__(256) void k_cvt2(const float* __restrict__ sa,
    const float* __restrict__ sb, unsigned short* __restrict__ da,
    unsigned short* __restrict__ db)
{
  const float* src = blockIdx.y ? sb : sa;
  unsigned short* dst = blockIdx.y ? db : da;
  int i = (blockIdx.x*256 + threadIdx.x)*4;
  float4 v = *(const float4*)&src[i];
  unsigned lo = (unsigned)f2bf(v.x) | ((unsigned)f2bf(v.y) << 16);
  unsigned hi = (unsigned)f2bf(v.z) | ((unsigned)f2bf(v.w) << 16);
  uint2 o; o.x = lo; o.y = hi;
  *(uint2*)&dst[i] = o;
}

// ------- fp32 [512][512] -> bf16 transposed, 4 arrays (blockIdx.y) ---------
__global__ __launch_bounds__(256) void k_cvt_t4(
    const float* __restrict__ w0, const float* __restrict__ w1,
    const float* __restrict__ w2, const float* __restrict__ w3,
    unsigned short* __restrict__ t0, unsigned short* __restrict__ t1,
    unsigned short* __restrict__ t2, unsigned short* __restrict__ t3)
{
  int wsel = blockIdx.y;
  const float* W = (wsel == 0) ? w0 : (wsel == 1) ? w1 : (wsel == 2) ? w2 : w3;
  unsigned short* Wt = (wsel == 0) ? t0 : (wsel == 1) ? t1 : (wsel == 2) ? t2 : t3;
  int idx = blockIdx.x*256 + threadIdx.x;
  int o = idx & 511;
  int ig = (idx >> 9) * 8;
  unsigned short r[8];
  #pragma unroll
  for (int j = 0; j < 8; ++j) r[j] = f2bf(W[(size_t)(ig + j)*512 + o]);
  uint4 v;
  v.x = (unsigned)r[0] | ((unsigned)r[1] << 16);
  v.y = (unsigned)r[2] | ((unsigned)r[3] << 16);
  v.z = (unsigned)r[4] | ((unsigned)r[5] << 16);
  v.w = (unsigned)r[6] | ((unsigned)r[7] << 16);
  *(uint4*)&Wt[(size_t)o*512 + ig] = v;
}

// ---------------- gather routed tokens -> bf16, pad to 448 ----------------
__global__ __launch_bounds__(256) void k_gather(const float* __restrict__ x,
    const int* __restrict__ idx, unsigned short* __restrict__ xg)
{
  int tid = threadIdx.x, lane = tid & 63, wid = tid >> 6;
  int gr = blockIdx.x*4 + wid;
  int b = gr / KPAD, r = gr - b*KPAD;
  uint4 o;
  if (r < KSEL) {
    int tok = idx[b*KSEL + r];
    size_t base = ((size_t)b*N_ + tok)*C_ + lane*8;
    float4 v0 = *(const float4*)&x[base];
    float4 v1 = *(const float4*)&x[base + 4];
    o.x = (unsigned)f2bf(v0.x) | ((unsigned)f2bf(v0.y) << 16);
    o.y = (unsigned)f2bf(v0.z) | ((unsigned)f2bf(v0.w) << 16);
    o.z = (unsigned)f2bf(v1.x) | ((unsigned)f2bf(v1.y) << 16);
    o.w = (unsigned)f2bf(v1.z) | ((unsigned)f2bf(v1.w) << 16);
  } else {
    o.x = o.y = o.z = o.w = 0u;
  }
  *(uint4*)&xg[(size_t)gr*C_ + lane*8] = o;
}

// ------- 256x128 tile single-buffered MFMA body, 512 threads (8 waves) -----
__device__ __forceinline__ void stage256(const unsigned short* __restrict__ Arows,
    const unsigned short* __restrict__ Brows, int k0,
    unsigned short* As, unsigned short* Bs, int srow, int spos)
{
  #pragma unroll
  for (int s = 0; s < 4; ++s) {            // A: 256 rows
    int row = s*64 + srow;
    int chunk = spos ^ (row & 7);
    gload16(&Arows[(size_t)row*C_ + k0 + chunk*8], &As[row*64 + spos*8]);
  }
  #pragma unroll
  for (int s = 0; s < 2; ++s) {            // B: 128 rows
    int row = s*64 + srow;
    int chunk = spos ^ (row & 7);
    gload16(&Brows[(size_t)row*C_ + k0 + chunk*8], &Bs[row*64 + spos*8]);
  }
}

__device__ __forceinline__ void gemm256_body(
    const unsigned short* __restrict__ Arows,
    const unsigned short* __restrict__ Brows,
    unsigned short* As, unsigned short* Bs, f32x4 acc[4][4])
{
  int tid = threadIdx.x;
  int lane = tid & 63, wid = tid >> 6;       // wid 0..7
  int wr = wid >> 1, wc = wid & 1;           // wave tile 64m x 64n of 256x128
  int srow = tid >> 3, spos = tid & 7;       // srow 0..63
  int l15 = lane & 15, lh = lane >> 4;
  for (int k0 = 0; k0 < C_; k0 += 64) {
    stage256(Arows, Brows, k0, As, Bs, srow, spos);
    __syncthreads();
    #pragma unroll
    for (int kk = 0; kk < 2; ++kk) {
      bf16x8 af[4], bfr[4];
      #pragma unroll
      for (int m = 0; m < 4; ++m) {
        int row = wr*64 + m*16 + l15;        // 0..255
        int chunk = (kk*4 + lh) ^ (row & 7);
        af[m] = *(const bf16x8*)&As[row*64 + chunk*8];
      }
      #pragma unroll
      for (int n = 0; n < 4; ++n) {
        int row = wc*64 + n*16 + l15;        // 0..127
        int chunk = (kk*4 + lh) ^ (row & 7);
        bfr[n] = *(const bf16x8*)&Bs[row*64 + chunk*8];
      }
      #pragma unroll
      for (int m = 0; m < 4; ++m)
        #pragma unroll
        for (int n = 0; n < 4; ++n)
          acc[m][n] = __builtin_amdgcn_mfma_f32_16x16x32_bf16(af[m], bfr[n], acc[m][n], 0, 0, 0);
    }
    __syncthreads();
  }
}

// ------- e = xn @ ea_k^T (256-row tile) + fused colsum ---------------------
__global__ __launch_bounds__(512) void k_eak_gemm(
    const unsigned short* __restrict__ A,
    const unsigned short* __restrict__ Bm,
    unsigned short* __restrict__ e, float* __restrict__ colsum)
{
  __shared__ unsigned short As[256*64];
  __shared__ unsigned short Bs[128*64];
  __shared__ float csum[128];
  int tid = threadIdx.x;
  int m0 = blockIdx.x * 256, n0 = blockIdx.y * 128;
  int lane = tid & 63, wid = tid >> 6;
  int wr = wid >> 1, wc = wid & 1;
  int l15 = lane & 15, lh = lane >> 4;
  f32x4 acc[4][4];
  #pragma unroll
  for (int m = 0; m < 4; ++m)
    #pragma unroll
    for (int n = 0; n < 4; ++n) acc[m][n] = (f32x4){0.f,0.f,0.f,0.f};
  gemm256_body(A + (size_t)m0*C_, Bm + (size_t)n0*C_, As, Bs, acc);
  if (tid < 128) csum[tid] = 0.f;
  __syncthreads();
  float pc[4] = {0.f, 0.f, 0.f, 0.f};
  #pragma unroll
  for (int m = 0; m < 4; ++m) {
    int row = m0 + wr*64 + m*16 + lh*4;
    #pragma unroll
    for (int n = 0; n < 4; ++n) {
      int col = n0 + wc*64 + n*16 + l15;
      #pragma unroll
      for (int r = 0; r < 4; ++r) {
        float v = acc[m][n][r] * 0.125f;
        e[(size_t)(row + r)*C_ + col] = f2bf(v);
        pc[n] += __expf(v);
      }
    }
  }
  #pragma unroll
  for (int n = 0; n < 4; ++n)
    atomicAdd(&csum[wc*64 + n*16 + l15], pc[n]);
  __syncthreads();
  int bb = m0 >> 12;   // 4096 rows per batch, 256-row tiles never span batches
  if (tid < 128) atomicAdd(&colsum[bb*C_ + n0 + tid], csum[tid]);
}

// ------- ea = a @ ea_v^T (256-row tile) + gathered SA add -> f32 out -------
__global__ __launch_bounds__(512) void k_eav_gemm(
    const unsigned short* __restrict__ A,
    const unsigned short* __restrict__ Bm,
    const int* __restrict__ inv, const float* __restrict__ sad,
    float* __restrict__ Co)
{
  __shared__ unsigned short As[256*64];
  __shared__ unsigned short Bs[128*64];
  int tid = threadIdx.x;
  int m0 = blockIdx.x * 256, n0 = blockIdx.y * 128;
  int lane = tid & 63, wid = tid >> 6;
  int wr = wid >> 1, wc = wid & 1;
  int l15 = lane & 15, lh = lane >> 4;
  f32x4 acc[4][4];
  #pragma unroll
  for (int m = 0; m < 4; ++m)
    #pragma unroll
    for (int n = 0; n < 4; ++n) acc[m][n] = (f32x4){0.f,0.f,0.f,0.f};
  gemm256_body(A + (size_t)m0*C_, Bm + (size_t)n0*C_, As, Bs, acc);
  #pragma unroll
  for (int m = 0; m < 4; ++m) {
    int rowl = wr*64 + m*16 + lh*4;
    #pragma unroll
    for (int r = 0; r < 4; ++r) {
      int row = m0 + rowl + r;            // global token row
      int iv = inv[row];
      int b = row >> 12;
      const float* sap = sad + ((size_t)(b*KPAD) + (iv < 0 ? 0 : iv))*C_;
      #pragma unroll
      for (int n = 0; n < 4; ++n) {
        int col = n0 + wc*64 + n*16 + l15;
        float v = acc[m][n][r];
        if (iv >= 0) v += sap[col];
        Co[(size_t)row*C_ + col] = v;
      }
    }
  }
}

// ------- 2-phase pipelined 128x128 body (64 KB LDS) for small grids --------
__device__ __forceinline__ void stage128(const unsigned short* __restrict__ Arows,
    const unsigned short* __restrict__ Brows, int k0,
    unsigned short* As, unsigned short* Bs, int srow, int spos)
{
  #pragma unroll
  for (int s = 0; s < 4; ++s) {
    int row = s*32 + srow;
    int chunk = spos ^ (row & 7);
    gload16(&Arows[(size_t)row*C_ + k0 + chunk*8], &As[row*64 + spos*8]);
    gload16(&Brows[(size_t)row*C_ + k0 + chunk*8], &Bs[row*64 + spos*8]);
  }
}

__device__ __forceinline__ void gemm128_pipe(
    const unsigned short* __restrict__ Arows,
    const unsigned short* __restrict__ Brows,
    unsigned short* As, unsigned short* Bs,   // each 2*8192 ushorts
    f32x4 acc[4][4])
{
  int tid = threadIdx.x;
  int lane = tid & 63, wid = tid >> 6;
  int wr = wid >> 1, wc = wid & 1;
  int srow = tid >> 3, spos = tid & 7;
  int l15 = lane & 15, lh = lane >> 4;
  stage128(Arows, Brows, 0, As, Bs, srow, spos);
  __syncthreads();
  for (int t = 0; t < 8; ++t) {
    int cur = (t & 1) ? 8192 : 0;
    int nxt = 8192 - cur;
    if (t < 7)
      stage128(Arows, Brows, (t+1)*64, As + nxt, Bs + nxt, srow, spos);
    #pragma unroll
    for (int kk = 0; kk < 2; ++kk) {
      bf16x8 af[4], bfr[4];
      #pragma unroll
      for (int m = 0; m < 4; ++m) {
        int row = wr*64 + m*16 + l15;
        int chunk = (kk*4 + lh) ^ (row & 7);
        af[m] = *(const bf16x8*)&As[cur + row*64 + chunk*8];
      }
      #pragma unroll
      for (int n = 0; n < 4; ++n) {
        int row = wc*64 + n*16 + l15;
        int chunk = (kk*4 + lh) ^ (row & 7);
        bfr[n] = *(const bf16x8*)&Bs[cur + row*64 + chunk*8];
      }
      #pragma unroll
      for (int m = 0; m < 4; ++m)
        #pragma unroll
        for (int n = 0; n < 4; ++n)
          acc[m][n] = __builtin_amdgcn_mfma_f32_16x16x32_bf16(af[m], bfr[n], acc[m][n], 0, 0, 0);
    }
    __syncthreads();
  }
}

// ---- QKV MFMA GEMM: z selects weight; coalesced LDS-repack epilogue ------
__global__ __launch_bounds__(256) void k_qkv_gemm(
    const unsigned short* __restrict__ xg,
    const unsigned short* __restrict__ wqt,
    const unsigned short* __restrict__ wkt,
    const unsigned short* __restrict__ wvt,
    unsigned short* __restrict__ qg, unsigned short* __restrict__ kg,
    unsigned short* __restrict__ vt)
{
  __shared__ unsigned short smem[32768];   // pipe: As|Bs; epilogue: 128x130 tile
  int tid = threadIdx.x;
  int m0 = blockIdx.x * 128, n0 = blockIdx.y * 128, w = blockIdx.z;
  const unsigned short* Wt = (w == 0) ? wqt : (w == 1) ? wkt : wvt;
  int lane = tid & 63, wid = tid >> 6;
  int wr = wid >> 1, wc = wid & 1;
  int l15 = lane & 15, lh = lane >> 4;
  f32x4 acc[4][4];
  #pragma unroll
  for (int m = 0; m < 4; ++m)
    #pragma unroll
    for (int n = 0; n < 4; ++n) acc[m][n] = (f32x4){0.f,0.f,0.f,0.f};
  gemm128_pipe(xg + (size_t)m0*C_, Wt + (size_t)n0*C_, smem, smem + 16384, acc);
  // pipe ends with __syncthreads(): smem free for repack
  float scale = (w == 0) ? 0.125f : 1.f;   // fold DH^-0.5 into Q
  const int TS = 130;                      // padded stride (odd dwords)
  #pragma unroll
  for (int m = 0; m < 4; ++m) {
    int rowl = wr*64 + m*16 + lh*4;
    #pragma unroll
    for (int n = 0; n < 4; ++n) {
      int col = wc*64 + n*16 + l15;
      #pragma unroll
      for (int r = 0; r < 4; ++r)
        smem[(rowl + r)*TS + col] = f2bf(acc[m][n][r] * scale);
    }
  }
  __syncthreads();
  int hbase = n0 >> 6;                     // 2 heads per 128-col tile
  if (w < 2) {
    unsigned short* dst = (w == 0) ? qg : kg;
    #pragma unroll
    for (int it = 0; it < 8; ++it) {
      int u = it*256 + tid;                // 0..2047
      int row = u >> 4, seg = u & 15;
      int mr = m0 + row;
      int b = mr / KPAD, rr = mr - b*KPAD;
      int h = hbase + (seg >> 3);
      int d0 = (seg & 7) * 8;
      const unsigned* sp = (const unsigned*)&smem[row*TS + seg*8];
      uint4 v; v.x = sp[0]; v.y = sp[1]; v.z = sp[2]; v.w = sp[3];
      *(uint4*)&dst[(((size_t)(b*H_ + h))*KPAD + rr)*DH_ + d0] = v;
    }
  } else {
    #pragma unroll
    for (int it = 0; it < 8; ++it) {
      int u = it*256 + tid;
      int d = u >> 4;                      // tile col 0..127
      int tg = u & 15;                     // token group (8 tokens)
      int mr = m0 + tg*8;
      int b = mr / KPAD, rr = mr - b*KPAD; // 8-aligned, never straddles batch
      int h = hbase + (d >> 6);
      int dd = d & 63;
      unsigned short tmp[8];
      #pragma unroll
      for (int k = 0; k < 8; ++k) tmp[k] = smem[(tg*8 + k)*TS + d];
      uint4 v;
      v.x = (unsigned)tmp[0] | ((unsigned)tmp[1] << 16);
      v.y = (unsigned)tmp[2] | ((unsigned)tmp[3] << 16);
      v.z = (unsigned)tmp[4] | ((unsigned)tmp[5] << 16);
      v.w = (unsigned)tmp[6] | ((unsigned)tmp[7] << 16);
      *(uint4*)&vt[(((size_t)(b*H_ + h))*DH_ + dd)*KPAD + rr] = v;
    }
  }
}

// ---------- MFMA flash attention (double-buffered K/V, 1 barrier/tile) -----
__global__ __launch_bounds__(256) void k_attn_mfma(
    const unsigned short* __restrict__ qg, const unsigned short* __restrict__ kg,
    const unsigned short* __restrict__ vt, unsigned short* __restrict__ sab)
{
  __shared__ unsigned short Qs[4096], Ps[4096];
  __shared__ unsigned short Ks[2][4096], Vs[2][4096];
  int tid = threadIdx.x, lane = tid & 63, wid = tid >> 6;
  int qt = blockIdx.x, h = blockIdx.y, b = blockIdx.z;
  int l15 = lane & 15, lh = lane >> 4;
  const unsigned short* qbase = qg + (((size_t)(b*H_ + h))*KPAD + qt*64)*DH_;
  const unsigned short* kbase = kg + ((size_t)(b*H_ + h))*KPAD*DH_;
  const unsigned short* vbase = vt + ((size_t)(b*H_ + h))*DH_*KPAD;
  int c0 = tid, c1 = tid + 256;
  int r0 = c0 >> 3, p0 = c0 & 7;
  int r1 = c1 >> 3, p1 = c1 & 7;
  gload16(&qbase[(size_t)r0*64 + (p0 ^ (r0 & 7))*8], &Qs[c0*8]);
  gload16(&qbase[(size_t)r1*64 + (p1 ^ (r1 & 7))*8], &Qs[c1*8]);
  gload16(&kbase[(size_t)r0*64 + (p0 ^ (r0 & 7))*8], &Ks[0][c0*8]);
  gload16(&kbase[(size_t)r1*64 + (p1 ^ (r1 & 7))*8], &Ks[0][c1*8]);
  gload16(&vbase[(size_t)r0*KPAD + (p0 ^ (r0 & 7))*8], &Vs[0][c0*8]);
  gload16(&vbase[(size_t)r1*KPAD + (p1 ^ (r1 & 7))*8], &Vs[0][c1*8]);
  __syncthreads();

  f32x4 acc_o[4];
  #pragma unroll
  for (int ct = 0; ct < 4; ++ct) acc_o[ct] = (f32x4){0.f,0.f,0.f,0.f};
  float m_run[4], l_run[4];
  #pragma unroll
  for (int r = 0; r < 4; ++r) { m_run[r] = -1e30f; l_run[r] = 0.f; }

  for (int t = 0; t < 7; ++t) {
    int cur = t & 1;
    if (t < 6) {
      int kt1 = (t+1)*64;
      int nb = cur ^ 1;
      gload16(&kbase[((size_t)(kt1 + r0))*64 + (p0 ^ (r0 & 7))*8], &Ks[nb][c0*8]);
      gload16(&kbase[((size_t)(kt1 + r1))*64 + (p1 ^ (r1 & 7))*8], &Ks[nb][c1*8]);
      gload16(&vbase[(size_t)r0*KPAD + kt1 + (p0 ^ (r0 & 7))*8], &Vs[nb][c0*8]);
      gload16(&vbase[(size_t)r1*KPAD + kt1 + (p1 ^ (r1 & 7))*8], &Vs[nb][c1*8]);
    }
    int kt0 = t*64;

    f32x4 s4[4];
    #pragma unroll
    for (int ct = 0; ct < 4; ++ct) s4[ct] = (f32x4){0.f,0.f,0.f,0.f};
    #pragma unroll
    for (int ks = 0; ks < 2; ++ks) {
      int qrow = wid*16 + l15;
      int qch = (ks*4 + lh) ^ (qrow & 7);
      bf16x8 qa = *(const bf16x8*)&Qs[qrow*64 + qch*8];
      #pragma unroll
      for (int ct = 0; ct < 4; ++ct) {
        int krow = ct*16 + l15;
        int kch = (ks*4 + lh) ^ (krow & 7);
        bf16x8 kb8 = *(const bf16x8*)&Ks[cur][krow*64 + kch*8];
        s4[ct] = __builtin_amdgcn_mfma_f32_16x16x32_bf16(qa, kb8, s4[ct], 0, 0, 0);
      }
    }

    bool valid[4];
    #pragma unroll
    for (int ct = 0; ct < 4; ++ct) valid[ct] = (kt0 + ct*16 + l15) < KSEL;
    #pragma unroll
    for (int r = 0; r < 4; ++r) {
      float sv[4];
      #pragma unroll
      for (int ct = 0; ct < 4; ++ct) sv[ct] = valid[ct] ? s4[ct][r] : -1e30f;
      float tm = fmaxf(fmaxf(sv[0], sv[1]), fmaxf(sv[2], sv[3]));
      #pragma unroll
      for (int off = 1; off < 16; off <<= 1) tm = fmaxf(tm, __shfl_xor(tm, off, 64));
      float mnew = fmaxf(m_run[r], tm);
      float corr = __expf(m_run[r] - mnew);
      float rs = 0.f;
      float p[4];
      #pragma unroll
      for (int ct = 0; ct < 4; ++ct) { p[ct] = __expf(sv[ct] - mnew); rs += p[ct]; }
      #pragma unroll
      for (int off = 1; off < 16; off <<= 1) rs += __shfl_xor(rs, off, 64);
      l_run[r] = l_run[r]*corr + rs;
      m_run[r] = mnew;
      #pragma unroll
      for (int ct = 0; ct < 4; ++ct) acc_o[ct][r] *= corr;
      int rowL = wid*16 + lh*4 + r;
      #pragma unroll
      for (int ct = 0; ct < 4; ++ct) {
        int col = ct*16 + l15;
        Ps[rowL*64 + ((col >> 3) ^ (rowL & 7))*8 + (col & 7)] = f2bf(p[ct]);
      }
    }

    #pragma unroll
    for (int ks = 0; ks < 2; ++ks) {
      int prow = wid*16 + l15;
      int pch = (ks*4 + lh) ^ (prow & 7);
      bf16x8 pa = *(const bf16x8*)&Ps[prow*64 + pch*8];
      #pragma unroll
      for (int ct = 0; ct < 4; ++ct) {
        int vrow = ct*16 + l15;
        int vch = (ks*4 + lh) ^ (vrow & 7);
        bf16x8 vb8 = *(const bf16x8*)&Vs[cur][vrow*64 + vch*8];
        acc_o[ct] = __builtin_amdgcn_mfma_f32_16x16x32_bf16(pa, vb8, acc_o[ct], 0, 0, 0);
      }
    }
    __syncthreads();
  }

  #pragma unroll
  for (int r = 0; r < 4; ++r) {
    int rg = qt*64 + wid*16 + lh*4 + r;
    float inv = 1.f / l_run[r];
    #pragma unroll
    for (int ct = 0; ct < 4; ++ct) {
      int col = h*64 + ct*16 + l15;
      unsigned short v = (rg < KSEL) ? f2bf(acc_o[ct][r] * inv) : (unsigned short)0;
      sab[((size_t)b*KPAD + rg)*C_ + col] = v;
    }
  }
}

// -------- out-proj MFMA GEMM -> DENSE sa_out = alpha*(sa@wo + bo) ----------
__global__ __launch_bounds__(256) void k_saout_gemm(
    const unsigned short* __restrict__ sab,
    const unsigned short* __restrict__ wot,
    const float* __restrict__ bo,
    const float* __restrict__ alphap, float* __restrict__ sad)
{
  __shared__ unsigned short As[2*8192];
  __shared__ unsigned short Bs[2*8192];
  int tid = threadIdx.x;
  int m0 = blockIdx.x * 128, n0 = blockIdx.y * 128;
  int lane = tid & 63, wid = tid >> 6;
  int wr = wid >> 1, wc = wid & 1;
  int l15 = lane & 15, lh = lane >> 4;
  f32x4 acc[4][4];
  #pragma unroll
  for (int m = 0; m < 4; ++m)
    #pragma unroll
    for (int n = 0; n < 4; ++n) acc[m][n] = (f32x4){0.f,0.f,0.f,0.f};
  gemm128_pipe(sab + (size_t)m0*C_, wot + (size_t)n0*C_, As, Bs, acc);
  float alpha = alphap[0];
  #pragma unroll
  for (int m = 0; m < 4; ++m) {
    int rowl = wr*64 + m*16 + lh*4;
    #pragma unroll
    for (int r = 0; r < 4; ++r) {
      int mr = m0 + rowl + r;            // = b*KPAD + rr
      #pragma unroll
      for (int n = 0; n < 4; ++n) {
        int col = n0 + wc*64 + n*16 + l15;
        sad[(size_t)mr*C_ + col] = alpha*(acc[m][n][r] + bo[col]);
      }
    }
  }
}

// ---------------- softmax value + head-normalize -> a (bf16) ----------------
__global__ __launch_bounds__(256) void k_anorm(const unsigned short* __restrict__ e,
    const float* __restrict__ colsum, unsigned short* __restrict__ ab)
{
  int tid = threadIdx.x, lane = tid & 63, wid = tid >> 6;
  int token = blockIdx.x*4 + wid;
  int b = token >> 12;
  size_t base = (size_t)token*C_ + lane*8;
  uint4 w = *(const uint4*)&e[base];
  float f[8];
  f[0] = __uint_as_float(w.x << 16); f[1] = __uint_as_float(w.x & 0xffff0000u);
  f[2] = __uint_as_float(w.y << 16); f[3] = __uint_as_float(w.y & 0xffff0000u);
  f[4] = __uint_as_float(w.z << 16); f[5] = __uint_as_float(w.z & 0xffff0000u);
  f[6] = __uint_as_float(w.w << 16); f[7] = __uint_as_float(w.w & 0xffff0000u);
  const float* cs = colsum + b*C_ + lane*8;
  float4 c0 = *(const float4*)&cs[0];
  float4 c1 = *(const float4*)&cs[4];
  float a[8];
  a[0] = __expf(f[0])/c0.x; a[1] = __expf(f[1])/c0.y;
  a[2] = __expf(f[2])/c0.z; a[3] = __expf(f[3])/c0.w;
  a[4] = __expf(f[4])/c1.x; a[5] = __expf(f[5])/c1.y;
  a[6] = __expf(f[6])/c1.z; a[7] = __expf(f[7])/c1.w;
  float hs = a[0]+a[1]+a[2]+a[3]+a[4]+a[5]+a[6]+a[7];
  hs += __shfl_xor(hs, 1, 64);
  hs += __shfl_xor(hs, 2, 64);
  hs += __shfl_xor(hs, 4, 64);
  hs += 1e-6f;
  float r = 1.f / hs;
  uint4 o;
  o.x = (unsigned)f2bf(a[0]*r) | ((unsigned)f2bf(a[1]*r) << 16);
  o.y = (unsigned)f2bf(a[2]*r) | ((unsigned)f2bf(a[3]*r) << 16);
  o.z = (unsigned)f2bf(a[4]*r) | ((unsigned)f2bf(a[5]*r) << 16);
  o.w = (unsigned)f2bf(a[6]*r) | ((unsigned)f2bf(a[7]*r) << 16);
  *(uint4*)&ab[base] = o;
}

extern "C" void kernel_launch(void* const* d_in, const int* in_sizes, int n_in,
                              void* d_out, int out_size, void* d_ws, size_t ws_size,
                              hipStream_t stream)
{
  const float* x     = (const float*)d_in[0];
  const float* temb  = (const float*)d_in[1];
  const float* g_w1  = (const float*)d_in[2];
  const float* g_b1  = (const float*)d_in[3];
  const float* g_w2  = (const float*)d_in[4];
  const float* g_b2  = (const float*)d_in[5];
  const float* wq    = (const float*)d_in[6];
  const float* wk    = (const float*)d_in[7];
  const float* wv    = (const float*)d_in[8];
  const float* wo    = (const float*)d_in[9];
  const float* bo    = (const float*)d_in[10];
  const float* ln_g  = (const float*)d_in[11];
  const float* ln_b  = (const float*)d_in[12];
  const float* ea_k  = (const float*)d_in[13];
  const float* ea_v  = (const float*)d_in[14];
  const float* alpha = (const float*)d_in[15];
  float* out = (float*)d_out;
  float* ws = (float*)d_ws;

  // workspace layout (float offsets)
  float* scores  = ws;                          // 4096 (dead after imp_prep)
  float* colsum  = ws;                          // alias (zeroed in topk)
  float* imp     = ws + 4096;                   // 32768 (dead after topk)
  int*   invm    = (int*)(ws + 4096);           // alias imp: inverse token map
  int*   idx     = (int*)(ws + 102400);         // 4096
  unsigned short* ebuf = (unsigned short*)(ws + 106496);    // 16777216 bf16
  unsigned short* xnb  = (unsigned short*)(ws + 8495104);   // 16777216 bf16 (xn, later a)
  unsigned short* eakb = (unsigned short*)(ws + 16883712);  // 262144 bf16
  unsigned short* eavb = (unsigned short*)(ws + 17014784);
  unsigned short* wqt  = (unsigned short*)(ws + 17145856);
  unsigned short* wkt  = (unsigned short*)(ws + 17276928);
  unsigned short* wvt  = (unsigned short*)(ws + 17408000);
  unsigned short* wot  = (unsigned short*)(ws + 17539072);
  unsigned short* xg   = (unsigned short*)(ws + 17670144);  // [8*448][512] bf16
  unsigned short* qg   = (unsigned short*)(ws + 18587648);  // [8][8][448][64] (dead after attn)
  unsigned short* kg   = (unsigned short*)(ws + 19505152);  //                 (dead after attn)
  unsigned short* vtb  = (unsigned short*)(ws + 20422656);  // [8][8][64][448] (dead after attn)
  unsigned short* sab  = (unsigned short*)(ws + 21340160);  // [8*448][512]
  float* sad = ws + 18587648;                   // dense SA out [8*448][512] f32, over qg/kg

  k_gating     <<<dim3(B_),          dim3(256), 0, stream>>>(temb, g_w1, g_b1, g_w2, g_b2, scores);
  k_imp_prep   <<<dim3(B_*N_/4),     dim3(256), 0, stream>>>(x, scores, ln_g, ln_b, imp, xnb);
  k_topk       <<<dim3(B_),          dim3(256), 0, stream>>>(imp, idx, invm, colsum);
  k_cvt2       <<<dim3(256, 2),      dim3(256), 0, stream>>>(ea_k, ea_v, eakb, eavb);
  k_cvt_t4     <<<dim3(128, 4),      dim3(256), 0, stream>>>(wq, wk, wv, wo, wqt, wkt, wvt, wot);
  k_gather     <<<dim3(B_*KPAD/4),   dim3(256), 0, stream>>>(x, idx, xg);
  k_qkv_gemm   <<<dim3(28, 4, 3),    dim3(256), 0, stream>>>(xg, wqt, wkt, wvt, qg, kg, vtb);
  k_attn_mfma  <<<dim3(7, H_, B_),   dim3(256), 0, stream>>>(qg, kg, vtb, sab);
  k_eak_gemm   <<<dim3(128, 4),      dim3(512), 0, stream>>>(xnb, eakb, ebuf, colsum);
  k_anorm      <<<dim3(B_*N_/4),     dim3(256), 0, stream>>>(ebuf, colsum, xnb);
  k_saout_gemm <<<dim3(28, 4),       dim3(256), 0, stream>>>(sab, wot, bo, alpha, sad);
  k_eav_gemm   <<<dim3(128, 4),      dim3(512), 0, stream>>>(xnb, eavb, invm, sad, out);
}